// Round 4
// baseline (914.464 us; speedup 1.0000x reference)
//
#include <hip/hip_runtime.h>
#include <hip/hip_bf16.h>

#define LRELU(v) ((v) > 0.f ? (v) : 0.2f * (v))
#define PSTR 768  // padded P row stride in floats ([node][64 lanes][12])

__device__ __forceinline__ void load10(float* d, const float* p) {
  // p is 16B-aligned (lane*48B offsets); reads 12 floats, keeps 10.
  float4 a = ((const float4*)p)[0];
  float4 b = ((const float4*)p)[1];
  float4 c = ((const float4*)p)[2];
  d[0] = a.x; d[1] = a.y; d[2] = a.z; d[3] = a.w;
  d[4] = b.x; d[5] = b.y; d[6] = b.z; d[7] = b.w;
  d[8] = c.x; d[9] = c.y;
}

__device__ __forceinline__ void store10(float* p, const float* s) {
  ((float4*)p)[0] = make_float4(s[0], s[1], s[2], s[3]);
  ((float4*)p)[1] = make_float4(s[4], s[5], s[6], s[7]);
  ((float4*)p)[2] = make_float4(s[8], s[9], 0.f, 0.f);
}

// ---------------------------------------------------------------------------
// lrelu(X[M,K] @ W[K,64] + b) -> out[M,64].  One wave per row.
__global__ __launch_bounds__(256) void embed_kernel(
    const float* __restrict__ X, const float* __restrict__ W,
    const float* __restrict__ b, float* __restrict__ out, int M, int K) {
  int lane = threadIdx.x & 63;
  int r = blockIdx.x * 4 + (threadIdx.x >> 6);
  if (r >= M) return;
  float acc = b[lane];
  const float* Xr = X + (size_t)r * K;
  for (int k = 0; k < K; ++k) acc = fmaf(Xr[k], W[(size_t)k * 64 + lane], acc);
  acc = LRELU(acc);
  out[(size_t)r * 64 + lane] = acc;
}

// Same but gathers input row via perm (fused permute): ea_s[p] = embed(edge_attr[perm[p]])
__global__ __launch_bounds__(256) void embed_perm_kernel(
    const float* __restrict__ X, const int* __restrict__ perm,
    const float* __restrict__ W, const float* __restrict__ b,
    float* __restrict__ out, int M, int K) {
  int lane = threadIdx.x & 63;
  int p = blockIdx.x * 4 + (threadIdx.x >> 6);
  if (p >= M) return;
  int r = perm[p];
  float acc = b[lane];
  const float* Xr = X + (size_t)r * K;
  for (int k = 0; k < K; ++k) acc = fmaf(Xr[k], W[(size_t)k * 64 + lane], acc);
  acc = LRELU(acc);
  out[(size_t)p * 64 + lane] = acc;
}

// ---------------------------------------------------------------------------
// conv_W (L,128,640) col=h*64+lane  ->  Wt (L,128,[64 lanes][12]) lane-major
__global__ void wtrans_kernel(const float* __restrict__ W,
                              float* __restrict__ Wt, int total) {
  int idx = blockIdx.x * 256 + threadIdx.x;
  if (idx >= total) return;
  int lane_h = idx % 640;
  int ik = idx / 640;
  int h = lane_h >> 6, lane = lane_h & 63;
  Wt[(size_t)ik * PSTR + lane * 12 + h] = W[idx];
}

// ---------------------------------------------------------------------------
// Counting sort of edges by row: hist -> scan -> scatter.
__global__ void hist_kernel(const int* __restrict__ row, int* __restrict__ hist,
                            int E_) {
  int e = blockIdx.x * 256 + threadIdx.x;
  if (e < E_) atomicAdd(&hist[row[e]], 1);
}

__global__ __launch_bounds__(1024) void scan_kernel(int* __restrict__ hist,
                                                    int* __restrict__ cursor,
                                                    int NB) {
  __shared__ int sums[1024];
  int t = threadIdx.x;
  int chunk = (NB + 1023) / 1024;
  int s0 = t * chunk;
  int local = 0;
  for (int j = 0; j < chunk; ++j) {
    int i = s0 + j;
    if (i < NB) local += hist[i];
  }
  sums[t] = local;
  __syncthreads();
  for (int off = 1; off < 1024; off <<= 1) {
    int add = (t >= off) ? sums[t - off] : 0;
    __syncthreads();
    sums[t] += add;
    __syncthreads();
  }
  int run = (t == 0) ? 0 : sums[t - 1];
  for (int j = 0; j < chunk; ++j) {
    int i = s0 + j;
    if (i < NB) {
      int v = hist[i];
      hist[i] = run;
      cursor[i] = run;
      run += v;
    }
  }
}

__global__ void scatter_kernel(const int* __restrict__ row,
                               const int* __restrict__ col,
                               int* __restrict__ cursor, int* __restrict__ perm,
                               int* __restrict__ srow, int* __restrict__ scol,
                               int E_) {
  int e = blockIdx.x * 256 + threadIdx.x;
  if (e >= E_) return;
  int r = row[e];
  int pos = atomicAdd(&cursor[r], 1);
  perm[pos] = e;
  srow[pos] = r;
  scol[pos] = col[e];
}

// ---------------------------------------------------------------------------
// Fused per-layer GEMM + state update.
// mode 0: A = hin (h0), no update.
// mode 1: hnew = 0.1*agg + b          ; write hout, zero agg, A = hnew
// mode 2: hnew = hin + 0.1*agg + b    ; write hout, zero agg, A = hnew
// Then P[r] = A[r] @ Wt (lane-major store).
__global__ __launch_bounds__(256) void gemm_update_kernel(
    const float* __restrict__ hin, float* __restrict__ hout,
    float* __restrict__ agg, const float* __restrict__ bvec,
    const float* __restrict__ Wt, float* __restrict__ P, int M, int mode) {
  const int lane = threadIdx.x & 63;
  const int r0 = (blockIdx.x * 4 + (threadIdx.x >> 6)) * 4;
  if (r0 >= M) return;
  float hreg[4];
#pragma unroll
  for (int r = 0; r < 4; ++r) {
    size_t idx = (size_t)(r0 + r) * 64 + lane;
    if (mode == 0) {
      hreg[r] = hin[idx];
    } else {
      float v = fmaf(agg[idx], 0.1f, bvec[lane]);
      if (mode == 2) v += hin[idx];
      hreg[r] = v;
      hout[idx] = v;
      agg[idx] = 0.f;
    }
  }
  float acc[4][10];
#pragma unroll
  for (int r = 0; r < 4; ++r)
#pragma unroll
    for (int h = 0; h < 10; ++h) acc[r][h] = 0.f;
  for (int k = 0; k < 64; ++k) {
    float w[10];
    load10(w, Wt + (size_t)k * PSTR + lane * 12);
    float a[4];
#pragma unroll
    for (int r = 0; r < 4; ++r) a[r] = __shfl(hreg[r], k);
#pragma unroll
    for (int r = 0; r < 4; ++r)
#pragma unroll
      for (int h = 0; h < 10; ++h) acc[r][h] = fmaf(a[r], w[h], acc[r][h]);
  }
#pragma unroll
  for (int r = 0; r < 4; ++r)
    store10(P + (size_t)(r0 + r) * PSTR + lane * 12, acc[r]);
}

// ---------------------------------------------------------------------------
// Fused: Q = ea_s@Wbot in-register (8 sorted edges/wave), prefetched P[col]
// pipeline, attention, run-merged scatter.
__global__ __launch_bounds__(256, 3) void edge_fused_kernel(
    const float* __restrict__ P, const float* __restrict__ ea_s,
    const float* __restrict__ Wt_bot,  // [64][64*12]
    const int* __restrict__ srow, const int* __restrict__ scol,
    const float* __restrict__ att, const float* __restrict__ gamma,
    const float* __restrict__ beta, float* __restrict__ agg, int E_) {
  const int lane = threadIdx.x & 63;
  const int e0 = (blockIdx.x * 4 + (threadIdx.x >> 6)) * 8;
  if (e0 >= E_) return;

  int rows[8], cols[8];
#pragma unroll
  for (int r = 0; r < 8; ++r) {
    int e = (e0 + r < E_) ? e0 + r : E_ - 1;
    rows[r] = srow[e];
    cols[r] = scol[e];
  }
  float eareg[8];
#pragma unroll
  for (int r = 0; r < 8; ++r) {
    int e = (e0 + r < E_) ? e0 + r : E_ - 1;
    eareg[r] = ea_s[(size_t)e * 64 + lane];
  }

  // Prefetch first two P[col] rows; GEMM below hides the latency.
  float pc0[10], pc1[10];
  load10(pc0, P + (size_t)cols[0] * PSTR + lane * 12);
  load10(pc1, P + (size_t)cols[1] * PSTR + lane * 12);

  float qacc[8][10];
#pragma unroll
  for (int r = 0; r < 8; ++r)
#pragma unroll
    for (int h = 0; h < 10; ++h) qacc[r][h] = 0.f;
  for (int k = 0; k < 64; ++k) {
    float w[10];
    load10(w, Wt_bot + (size_t)k * PSTR + lane * 12);
    float a[8];
#pragma unroll
    for (int r = 0; r < 8; ++r) a[r] = __shfl(eareg[r], k);
#pragma unroll
    for (int r = 0; r < 8; ++r)
#pragma unroll
      for (int h = 0; h < 10; ++h) qacc[r][h] = fmaf(a[r], w[h], qacc[r][h]);
  }

  float att1[10], att2[10];
#pragma unroll
  for (int h = 0; h < 10; ++h) {
    att1[h] = att[h * 128 + lane];
    att2[h] = att[h * 128 + 64 + lane];
  }

  const float inv_std = 0.9999950000374997f;  // 1/sqrt(1+1e-5)
  float pr[10];
  int curRow = -1;
  float macc = 0.f;
  int prev = rows[0];
#pragma unroll
  for (int r = 0; r < 8; ++r) {
    int e = e0 + r;
    if (e >= E_) break;
    int ri = rows[r], ci = cols[r];
    (void)ci;
    float pcl[10];
#pragma unroll
    for (int h = 0; h < 10; ++h) pcl[h] = (r & 1) ? pc1[h] : pc0[h];
    if (r + 2 < 8) {  // prefetch edge r+2 into the buffer just freed
      if (r & 1)
        load10(pc1, P + (size_t)cols[r + 2] * PSTR + lane * 12);
      else
        load10(pc0, P + (size_t)cols[r + 2] * PSTR + lane * 12);
    }
    if (ri != curRow) {  // wave-uniform
      curRow = ri;
      load10(pr, P + (size_t)ri * PSTR + lane * 12);
    }
    float hj[10], val[10];
#pragma unroll
    for (int h = 0; h < 10; ++h) {
      float q = qacc[r][h];
      float hi = pr[h] + q;
      float hjv = pcl[h] + q;
      hi = LRELU(hi);
      hjv = LRELU(hjv);
      hj[h] = hjv;
      val[h] = fmaf(hi, att1[h], hjv * att2[h]);
    }
#pragma unroll
    for (int h = 0; h < 10; ++h) {
      float v = val[h];
#pragma unroll
      for (int off = 32; off; off >>= 1) v += __shfl_xor(v, off);
      val[h] = v;
    }
    float mx = -1e30f;
#pragma unroll
    for (int h = 0; h < 10; ++h) {
      float a = val[h];
      a = LRELU(a);
      a = fmaf(a * inv_std, gamma[h], beta[h]);
      val[h] = a;
      mx = fmaxf(mx, a);
    }
    float ssum = 0.f;
#pragma unroll
    for (int h = 0; h < 10; ++h) {
      float ex = __expf(val[h] - mx);
      val[h] = ex;
      ssum += ex;
    }
    float inv = 1.0f / ssum;
    float m = 0.f;
#pragma unroll
    for (int h = 0; h < 10; ++h) m = fmaf(val[h] * inv, hj[h], m);
    if (ri != prev) {  // wave-uniform: flush previous run
      atomicAdd(agg + (size_t)prev * 64 + lane, macc);
      macc = 0.f;
      prev = ri;
    }
    macc += m;
  }
  atomicAdd(agg + (size_t)prev * 64 + lane, macc);
}

// ---------------------------------------------------------------------------
// Final: h = h + 0.1*agg + b + h0
__global__ __launch_bounds__(256) void finalize_kernel(
    float* __restrict__ h, const float* __restrict__ agg,
    const float* __restrict__ b, const float* __restrict__ h0, int total) {
  int idx = blockIdx.x * 256 + threadIdx.x;
  if (idx >= total) return;
  int f = idx & 63;
  h[idx] = h[idx] + fmaf(agg[idx], 0.1f, b[f]) + h0[idx];
}

// ---------------------------------------------------------------------------
__global__ __launch_bounds__(256) void score_kernel(
    const float* __restrict__ h, const int* __restrict__ batch,
    const float* __restrict__ gf, const float* __restrict__ W1,
    const float* __restrict__ b1, const float* __restrict__ W2,
    const float* __restrict__ b2, float* __restrict__ score, int N_) {
  int lane = threadIdx.x & 63;
  int n = blockIdx.x * 4 + (threadIdx.x >> 6);
  if (n >= N_) return;
  float acc = b1[lane];
  const float* hn = h + (size_t)n * 64;
#pragma unroll 8
  for (int k = 0; k < 64; ++k) acc = fmaf(hn[k], W1[k * 64 + lane], acc);
  const float* g = gf + (size_t)batch[n] * 108;
#pragma unroll 4
  for (int k = 0; k < 108; ++k) acc = fmaf(g[k], W1[(64 + k) * 64 + lane], acc);
  acc = LRELU(acc);
  float v = acc * W2[lane];
#pragma unroll
  for (int off = 32; off; off >>= 1) v += __shfl_xor(v, off);
  if (lane == 0) score[n] = v + b2[0];
}

// ---------------------------------------------------------------------------
__global__ void bounds_kernel(const int* __restrict__ batch,
                              int* __restrict__ start, int N_, int G_) {
  int n = blockIdx.x * blockDim.x + threadIdx.x;
  if (n >= N_) return;
  int b = batch[n];
  int bp = (n == 0) ? -1 : batch[n - 1];
  for (int g = bp + 1; g <= b; ++g) start[g] = n;
  if (n == N_ - 1)
    for (int g = b + 1; g <= G_; ++g) start[g] = N_;
}

// ---------------------------------------------------------------------------
__global__ __launch_bounds__(256) void pool_out_kernel(
    const float* __restrict__ h, const float* __restrict__ score,
    const int* __restrict__ start, const float* __restrict__ W1,
    const float* __restrict__ b1, const float* __restrict__ W2,
    const float* __restrict__ b2, float* __restrict__ out) {
  int g = blockIdx.x;
  int s0 = start[g], s1 = start[g + 1];
  int tid = threadIdx.x;
  __shared__ float red[256];
  __shared__ float pool[64];
  __shared__ float sh_smax, sh_denom;
  float lm = -1e30f;
  for (int n = s0 + tid; n < s1; n += 256) lm = fmaxf(lm, score[n]);
  red[tid] = lm;
  __syncthreads();
  for (int off = 128; off; off >>= 1) {
    if (tid < off) red[tid] = fmaxf(red[tid], red[tid + off]);
    __syncthreads();
  }
  if (tid == 0) sh_smax = red[0];
  __syncthreads();
  float smax = sh_smax;
  __syncthreads();
  float ls = 0.f;
  for (int n = s0 + tid; n < s1; n += 256) ls += __expf(score[n] - smax);
  red[tid] = ls;
  __syncthreads();
  for (int off = 128; off; off >>= 1) {
    if (tid < off) red[tid] += red[tid + off];
    __syncthreads();
  }
  if (tid == 0) sh_denom = red[0];
  __syncthreads();
  float denom = sh_denom;
  float invd = denom > 0.f ? 1.0f / denom : 0.f;
  __syncthreads();
  int f = tid & 63, sub = tid >> 6;
  float acc = 0.f;
  for (int n = s0 + sub; n < s1; n += 4)
    acc = fmaf(__expf(score[n] - smax), h[(size_t)n * 64 + f], acc);
  red[tid] = acc;
  __syncthreads();
  if (tid < 64)
    pool[tid] = (red[tid] + red[tid + 64] + red[tid + 128] + red[tid + 192]) * invd;
  __syncthreads();
  if (tid < 64) {
    float a = b1[tid];
#pragma unroll 8
    for (int k = 0; k < 64; ++k) a = fmaf(pool[k], W1[k * 64 + tid], a);
    a = fmaxf(a, 0.f);
    red[tid] = a * W2[tid];
  }
  __syncthreads();
  if (tid == 0) {
    float s = 0.f;
    for (int k = 0; k < 64; ++k) s += red[k];
    out[g] = s + b2[0];
  }
}

// ---------------------------------------------------------------------------
extern "C" void kernel_launch(void* const* d_in, const int* in_sizes, int n_in,
                              void* d_out, int out_size, void* d_ws,
                              size_t ws_size, hipStream_t stream) {
  const float* x          = (const float*)d_in[0];
  const int*   edge_index = (const int*)d_in[1];
  const float* edge_attr  = (const float*)d_in[2];
  const int*   batch_idx  = (const int*)d_in[3];
  const float* gf         = (const float*)d_in[4];
  const float* node_W     = (const float*)d_in[5];
  const float* node_b     = (const float*)d_in[6];
  const float* edge_W     = (const float*)d_in[7];
  const float* edge_b     = (const float*)d_in[8];
  const float* conv_W     = (const float*)d_in[9];
  const float* conv_att   = (const float*)d_in[10];
  const float* conv_b     = (const float*)d_in[11];
  const float* conv_gamma = (const float*)d_in[12];
  const float* conv_beta  = (const float*)d_in[13];
  const float* ga_W1      = (const float*)d_in[14];
  const float* ga_b1      = (const float*)d_in[15];
  const float* ga_W2      = (const float*)d_in[16];
  const float* ga_b2      = (const float*)d_in[17];
  const float* out_W1     = (const float*)d_in[18];
  const float* out_b1     = (const float*)d_in[19];
  const float* out_W2     = (const float*)d_in[20];
  const float* out_b2     = (const float*)d_in[21];
  float* out = (float*)d_out;

  const int N = in_sizes[3];        // 10000
  const int E = in_sizes[2] / 50;   // 40000
  const int G = in_sizes[4] / 108;  // 128
  const int L = 5;

  float* ws = (float*)d_ws;
  float* h    = ws;  ws += (size_t)N * 64;
  float* h0   = ws;  ws += (size_t)N * 64;
  float* ea_s = ws;  ws += (size_t)E * 64;
  float* P    = ws;  ws += (size_t)N * PSTR;
  float* Wt   = ws;  ws += (size_t)L * 128 * PSTR;
  float* agg  = ws;  ws += (size_t)N * 64;
  float* scr  = ws;  ws += N;
  int* gstart = (int*)ws;  ws += G + 2;
  int* hist   = (int*)ws;  ws += N;
  int* cursor = (int*)ws;  ws += N;
  int* perm   = (int*)ws;  ws += E;
  int* srow   = (int*)ws;  ws += E;
  int* scol   = (int*)ws;  ws += E;

  const int* row = edge_index;
  const int* col = edge_index + E;

  hipMemsetAsync(hist, 0, (size_t)N * sizeof(int), stream);
  hipMemsetAsync(agg, 0, (size_t)N * 64 * sizeof(float), stream);

  hist_kernel<<<(E + 255) / 256, 256, 0, stream>>>(row, hist, E);
  scan_kernel<<<1, 1024, 0, stream>>>(hist, cursor, N);
  scatter_kernel<<<(E + 255) / 256, 256, 0, stream>>>(row, col, cursor, perm,
                                                      srow, scol, E);
  wtrans_kernel<<<(L * 128 * 640 + 255) / 256, 256, 0, stream>>>(
      conv_W, Wt, L * 128 * 640);

  embed_kernel<<<(N + 3) / 4, 256, 0, stream>>>(x, node_W, node_b, h0, N, 92);
  embed_perm_kernel<<<(E + 3) / 4, 256, 0, stream>>>(edge_attr, perm, edge_W,
                                                     edge_b, ea_s, E, 50);

  for (int i = 0; i < L; ++i) {
    const float* Wti = Wt + (size_t)i * 128 * PSTR;
    int mode = (i == 0) ? 0 : (i == 1 ? 1 : 2);
    gemm_update_kernel<<<(N + 15) / 16, 256, 0, stream>>>(
        i == 0 ? h0 : h, h, agg, conv_b + (i - 1) * 64, Wti, P, N, mode);
    int waves = (E + 7) / 8;
    edge_fused_kernel<<<(waves + 3) / 4, 256, 0, stream>>>(
        P, ea_s, Wti + (size_t)64 * PSTR, srow, scol,
        conv_att + (size_t)i * 1280, conv_gamma + i * 10, conv_beta + i * 10,
        agg, E);
  }
  finalize_kernel<<<(N * 64 + 255) / 256, 256, 0, stream>>>(
      h, agg, conv_b + 4 * 64, h0, N * 64);

  score_kernel<<<(N + 3) / 4, 256, 0, stream>>>(h, batch_idx, gf, ga_W1, ga_b1,
                                                ga_W2, ga_b2, scr, N);
  bounds_kernel<<<(N + 255) / 256, 256, 0, stream>>>(batch_idx, gstart, N, G);
  pool_out_kernel<<<G, 256, 0, stream>>>(h, scr, gstart, out_W1, out_b1, out_W2,
                                         out_b2, out);
}